// Round 9
// baseline (193.356 us; speedup 1.0000x reference)
//
#include <hip/hip_runtime.h>

// Gammatone filterbank, truncated-history, stage-skewed, scalar-FMA form.
// v9: FULL-LINE STORES FROM ONE WORKGROUP. v1-v8 split the 128 channels
// across two 64-thread blocks: every 512 B output row (out[b][t][0..127])
// was written half by a g=0 block and half by a g=1 block -- different
// workgroups on DIFFERENT XCDs (round-robin dispatch), ~30 us apart in
// time (6x different warm-up). The two 256 B partials could never merge
// (per-XCD L2s are not coherent), so DRAM saw hole-strided 256 B writes
// from each XCD -- a plausible ~2x write-efficiency loss, invisible to
// every lever tried so far (TLP/makespan/ILP/codegen/nt -- all null).
// Fix: one 128-thread block (2 waves) owns all 128 channels of a chunk;
// each time-step's 512 B line-pair is written by one CU/XCD/L2, and a
// barrier per 4 samples keeps both waves' halves within ~100 cyc so L2
// merges full lines. Same total occupancy (512x2 waves = 1 wave/SIMD).
// Both waves use the block-max warm-up W (channel 0): identical control
// flow, legal barriers; the extra g=1 warm-up is free (v5: makespan slack
// doesn't move the floor).

#define B_N    8
#define T_LEN  32000
#define C_CH   128
#define L_CHK  500
#define NB     64          // T_LEN / L_CHK
#define W_MAX  1024

// One skewed pipeline step, consuming x[i+3] (skew from v2: at iter i,
// regs hold s1=y1[i+2], s2=y2[i+1], s3=y3[i], s4=y4[i-1]; all updates
// read pre-update values -> 4 independent 2-FMA chains).
#define PSTEP(XR) do {                                        \
    float n4r = fmaf(cr, s4r, s3r); n4r = fmaf(mci, s4i, n4r); \
    float n4i = fmaf(cr, s4i, s3i); n4i = fmaf(ci,  s4r, n4i); \
    float n3r = fmaf(cr, s3r, s2r); n3r = fmaf(mci, s3i, n3r); \
    float n3i = fmaf(cr, s3i, s2i); n3i = fmaf(ci,  s3r, n3i); \
    float n2r = fmaf(cr, s2r, s1r); n2r = fmaf(mci, s2i, n2r); \
    float n2i = fmaf(cr, s2i, s1i); n2i = fmaf(ci,  s2r, n2i); \
    float n1r = fmaf(cr, s1r, (XR)); n1r = fmaf(mci, s1i, n1r);\
    float n1i = cr * s1i;           n1i = fmaf(ci,  s1r, n1i); \
    s4r = n4r; s4i = n4i; s3r = n3r; s3i = n3i;               \
    s2r = n2r; s2i = n2i; s1r = n1r; s1i = n1i;               \
} while (0)

__global__ __launch_bounds__(128, 1) void gt_trunc(
    const float* __restrict__ x, const float* __restrict__ cre,
    const float* __restrict__ cim, const float* __restrict__ fac,
    float* __restrict__ out)
{
    __shared__ __align__(16) float xs[W_MAX + L_CHK + 16];
    const int k  = blockIdx.x;            // time chunk
    const int b  = blockIdx.y;            // batch
    const int c  = threadIdx.x;           // channel 0..127
    const int t0 = k * L_CHK;

    // Block-uniform warm-up length from channel 0 (largest |c|). A=14
    // (validated v5/v7/v8: absmax stays at the 0.00390625 harness floor).
    const float cr0 = cre[0], ci0 = cim[0];
    const float negln = -0.5f * __logf(cr0 * cr0 + ci0 * ci0);   // -ln|c|
    int W = (int)ceilf(14.0f / negln) + 2;
    W = (W + 3) & ~3;                      // multiple of 4 (float4 LDS reads)
    if (W > W_MAX) W = W_MAX;
    int start = t0 - W;
    if (start < 0) start = 0;              // early chunks: zero init is exact
    const int n  = t0 + L_CHK - start;     // staged samples (multiple of 4)
    const int nw = t0 - start;             // warm-up steps (multiple of 4)

    // Stage x[start .. t0+L) into LDS at xs[1..n] (shift by 1: skewed
    // consumption index i+3 lands on aligned quads), coalesced. Zero-fill
    // 12 tail slots (2-deep prefetch reads up to xs[nw+511]; past-n data
    // only feeds dead s1..s3 but must not be garbage).
    const float* xb = x + (size_t)b * T_LEN + start;
    for (int i = threadIdx.x; i < n; i += 128) xs[i + 1] = xb[i];
    if (threadIdx.x < 12) xs[n + 1 + threadIdx.x] = 0.f;

    const float cr = cre[c], ci = cim[c], f = fac[c];
    const float mci = -ci;
    __syncthreads();

    // Pipeline fill in closed form from zero state (x0..x2 = xs[1..3]):
    //   y1[0]=(x0,0); y1[1]=c*y1[0]+x1; s1=y1[2]=c*y1[1]+x2;
    //   y2[0]=y1[0];  s2=y2[1]=c*y2[0]+y1[1]; s3=y3[0]=(x0,0); s4=0.
    const float x0 = xs[1], x1 = xs[2], x2 = xs[3];
    const float y11r = fmaf(cr, x0, x1);
    const float y11i = ci * x0;
    float s1r = fmaf(mci, y11i, fmaf(cr, y11r, x2));
    float s1i = fmaf(ci, y11r, cr * y11i);
    float s2r = fmaf(cr, x0, y11r);
    float s2i = fmaf(ci, x0, y11i);
    float s3r = x0, s3i = 0.f;
    float s4r = 0.f, s4i = 0.f;

    // Warm-up (no stores). 2-deep software pipeline; identical trip count
    // for both waves (block-uniform nw).
    float4 q0 = *(const float4*)&xs[4];
    float4 q1 = *(const float4*)&xs[8];
    for (int i = 0; i < nw; i += 4) {
        const float4 q2 = *(const float4*)&xs[i + 12];
        PSTEP(q0.x); PSTEP(q0.y); PSTEP(q0.z); PSTEP(q0.w);
        q0 = q1; q1 = q2;
    }
    // loop exit: q0 = xs[nw+4..7], q1 = xs[nw+8..11]

    // Output region: after the step at iteration i, s4 = y4[i]; store for
    // i >= nw. Each time-step: 128 threads write the FULL 512 B line-pair
    // out[b][t][0..127] from one workgroup; the barrier keeps both waves'
    // halves temporally adjacent so L2 assembles full lines.
    float* op = out + ((size_t)b * T_LEN + t0) * C_CH + c;
    for (int i = nw; i < nw + L_CHK; i += 4) {
        const float4 q2 = *(const float4*)&xs[i + 12];
        PSTEP(q0.x); op[0 * C_CH] = s4r * f;
        PSTEP(q0.y); op[1 * C_CH] = s4r * f;
        PSTEP(q0.z); op[2 * C_CH] = s4r * f;
        PSTEP(q0.w); op[3 * C_CH] = s4r * f;
        op += 4 * (size_t)C_CH;
        q0 = q1; q1 = q2;
        __syncthreads();
    }
}

extern "C" void kernel_launch(void* const* d_in, const int* in_sizes, int n_in,
                              void* d_out, int out_size, void* d_ws, size_t ws_size,
                              hipStream_t stream) {
    const float* x   = (const float*)d_in[0];
    const float* cre = (const float*)d_in[1];
    const float* cim = (const float*)d_in[2];
    const float* fac = (const float*)d_in[3];
    float* out = (float*)d_out;

    gt_trunc<<<dim3(NB, B_N), 128, 0, stream>>>(x, cre, cim, fac, out);
}

// Round 10
// 154.684 us; speedup vs baseline: 1.2500x; 1.2500x over previous
//
#include <hip/hip_runtime.h>

// Gammatone filterbank, truncated-history, stage-skewed, PACKED-FMA form.
// v10: force v_pk_fma_f32. v9's counters: VALUBusy 32%, HBM 18%, LDS
// conflicts 0 -> not memory-bound; wave stalls ~68% but the VALU issue
// floor is real: 16 scalar FMA/sample x 2cyc = 32 cyc/sample/wave, and
// v2 runs at 113 cyc/sample (busy 28% == measured 32%). v7 (f32x2+.yx)
// == v8 (scalar) showed the compiler never emits packed FMAs for the
// complex swizzle. CDNA4 VOP3P v_pk_fma_f32 does 2 FMAs per 2-cyc slot,
// and op_sel folds the real<->imag swap: one complex one-pole stage = 2
// instructions, 8 VALU instr/sample total (issue floor 16 cyc/sample).
// Structure = v7 (64-thr blocks, no barriers -- v9's cost 18us; 2-deep
// LDS prefetch; A=14 warm-up, all validated at absmax floor 0.0039).
// Skew (v2): at iter i regs hold s1=y1[i+2], s2=y2[i+1], s3=y3[i],
// s4=y4[i-1]; the 4 stage updates read pre-update values -> independent.

typedef float f32x2 __attribute__((ext_vector_type(2)));

#define B_N    8
#define T_LEN  32000
#define C_CH   128
#define L_CHK  500
#define NB     64          // T_LEN / L_CHK
#define W_MAX  1024

// n = c * s + add  (complex), c pre-split as crr=(cr,cr), cni=(-ci,ci):
//   t = (cr*sr+ar, cr*si+ai)                   v_pk_fma_f32, no modifiers
//   n = (-ci*si+t.lo, ci*sr+t.hi)              v_pk_fma_f32, b swapped:
//       lo lane reads s.hi (op_sel b=1), hi lane reads s.lo (op_sel_hi b=0)
static __device__ __forceinline__ f32x2 cstep(f32x2 s, f32x2 add,
                                              f32x2 crr, f32x2 cni) {
    f32x2 t, n;
    asm("v_pk_fma_f32 %0, %1, %2, %3"
        : "=v"(t) : "v"(crr), "v"(s), "v"(add));
    asm("v_pk_fma_f32 %0, %1, %2, %3 op_sel:[0,1,0] op_sel_hi:[1,0,1]"
        : "=v"(n) : "v"(cni), "v"(s), "v"(t));
    return n;
}

// One skewed pipeline step, consuming x[i+3]: 8 pk-FMA instructions.
#define PSTEP(XR) do {                               \
    const f32x2 xin = {(XR), 0.f};                   \
    const f32x2 n4 = cstep(s4, s3, crr, cni);        \
    const f32x2 n3 = cstep(s3, s2, crr, cni);        \
    const f32x2 n2 = cstep(s2, s1, crr, cni);        \
    const f32x2 n1 = cstep(s1, xin, crr, cni);       \
    s4 = n4; s3 = n3; s2 = n2; s1 = n1;              \
} while (0)

__global__ __launch_bounds__(64, 1) void gt_trunc(
    const float* __restrict__ x, const float* __restrict__ cre,
    const float* __restrict__ cim, const float* __restrict__ fac,
    float* __restrict__ out)
{
    __shared__ __align__(16) float xs[W_MAX + L_CHK + 16];
    const int g  = blockIdx.x;            // channel half (0: ch 0-63, 1: ch 64-127)
    const int k  = blockIdx.y;            // time chunk
    const int b  = blockIdx.z;            // batch
    const int c  = g * 64 + threadIdx.x;
    const int t0 = k * L_CHK;

    // Warm-up length from the largest-|c| channel of this half. A=14
    // (validated v5/v7/v8: absmax stays at the 0.00390625 harness floor).
    const float cr0 = cre[g * 64], ci0 = cim[g * 64];
    const float negln = -0.5f * __logf(cr0 * cr0 + ci0 * ci0);   // -ln|c|
    int W = (int)ceilf(14.0f / negln) + 2;
    W = (W + 3) & ~3;                      // multiple of 4 (float4 LDS reads)
    if (W > W_MAX) W = W_MAX;
    int start = t0 - W;
    if (start < 0) start = 0;              // early chunks: zero init is exact
    const int n  = t0 + L_CHK - start;     // staged samples (multiple of 4)
    const int nw = t0 - start;             // warm-up steps (multiple of 4)

    // Stage x[start .. t0+L) into LDS at xs[1..n] (shift by 1: skewed
    // consumption index i+3 lands on aligned quads), coalesced. Zero-fill
    // 12 tail slots (2-deep prefetch reads up to xs[nw+511]; past-n data
    // only feeds dead s1..s3 but must not be garbage).
    const float* xb = x + (size_t)b * T_LEN + start;
    for (int i = threadIdx.x; i < n; i += 64) xs[i + 1] = xb[i];
    if (threadIdx.x < 12) xs[n + 1 + threadIdx.x] = 0.f;

    const float cr = cre[c], ci = cim[c], f = fac[c];
    const f32x2 crr = {cr, cr};
    const f32x2 cni = {-ci, ci};
    __syncthreads();

    // Pipeline fill in closed form from zero state (x0..x2 = xs[1..3]):
    //   y1[0]=(x0,0); y1[1]=c*y1[0]+x1; s1=y1[2]=c*y1[1]+x2;
    //   y2[0]=y1[0];  s2=y2[1]=c*y2[0]+y1[1]; s3=y3[0]=(x0,0); s4=0.
    const float x0 = xs[1], x1 = xs[2], x2 = xs[3];
    const float y11r = fmaf(cr, x0, x1);
    const float y11i = ci * x0;
    f32x2 s1 = {fmaf(-ci, y11i, fmaf(cr, y11r, x2)),
                fmaf(ci, y11r, cr * y11i)};
    f32x2 s2 = {fmaf(cr, x0, y11r), fmaf(ci, x0, y11i)};
    f32x2 s3 = {x0, 0.f};
    f32x2 s4 = {0.f, 0.f};

    // Warm-up (no stores). 2-deep software pipeline (v7).
    float4 q0 = *(const float4*)&xs[4];
    float4 q1 = *(const float4*)&xs[8];
    #pragma unroll 2
    for (int i = 0; i < nw; i += 4) {
        const float4 q2 = *(const float4*)&xs[i + 12];
        PSTEP(q0.x); PSTEP(q0.y); PSTEP(q0.z); PSTEP(q0.w);
        q0 = q1; q1 = q2;
    }
    // loop exit: q0 = xs[nw+4..7], q1 = xs[nw+8..11]

    // Output region: after the step at iteration i, s4 = y4[i]; store for
    // i >= nw. One coalesced 256 B wave-store per time step; gain applied
    // at store (filter is linear).
    float* op = out + ((size_t)b * T_LEN + t0) * C_CH + c;
    #pragma unroll 2
    for (int i = nw; i < nw + L_CHK; i += 4) {
        const float4 q2 = *(const float4*)&xs[i + 12];
        PSTEP(q0.x); op[0 * C_CH] = s4.x * f;
        PSTEP(q0.y); op[1 * C_CH] = s4.x * f;
        PSTEP(q0.z); op[2 * C_CH] = s4.x * f;
        PSTEP(q0.w); op[3 * C_CH] = s4.x * f;
        op += 4 * (size_t)C_CH;
        q0 = q1; q1 = q2;
    }
}

extern "C" void kernel_launch(void* const* d_in, const int* in_sizes, int n_in,
                              void* d_out, int out_size, void* d_ws, size_t ws_size,
                              hipStream_t stream) {
    const float* x   = (const float*)d_in[0];
    const float* cre = (const float*)d_in[1];
    const float* cim = (const float*)d_in[2];
    const float* fac = (const float*)d_in[3];
    float* out = (float*)d_out;

    gt_trunc<<<dim3(2, NB, B_N), 64, 0, stream>>>(x, cre, cim, fac, out);
}